// Round 1
// baseline (51.686 us; speedup 1.0000x reference)
//
#include <hip/hip_runtime.h>

#define HWE 131072   // 256*512 env pixels
#define OPIX 16384   // 128*128 output pixels
#define NG 8         // groups splitting the 64 (pass,n) pairs

// Pack per env pixel: [x0.rgb, y0.rgb, (x1-y1).rgb, (x2-y2).rgb, (x3-y3).rgb, pad]
// -> 16 floats = 64B = one cache line per gather position.
__global__ __launch_bounds__(256) void k_repack(
    const float* __restrict__ x, const float* __restrict__ y,
    float* __restrict__ env) {
  int pix = blockIdx.x * 256 + threadIdx.x;
  float o[16];
  #pragma unroll
  for (int b = 0; b < 4; b++) {
    float xv0 = x[(size_t)(b * HWE + pix) * 3 + 0];
    float xv1 = x[(size_t)(b * HWE + pix) * 3 + 1];
    float xv2 = x[(size_t)(b * HWE + pix) * 3 + 2];
    float yv0 = y[(size_t)(b * HWE + pix) * 3 + 0];
    float yv1 = y[(size_t)(b * HWE + pix) * 3 + 1];
    float yv2 = y[(size_t)(b * HWE + pix) * 3 + 2];
    if (b == 0) {
      o[0] = xv0; o[1] = xv1; o[2] = xv2;
      o[3] = yv0; o[4] = yv1; o[5] = yv2;
    } else {
      o[3 + b * 3 + 0] = xv0 - yv0;
      o[3 + b * 3 + 1] = xv1 - yv1;
      o[3 + b * 3 + 2] = xv2 - yv2;
    }
  }
  o[15] = 0.f;
  float4* dst = (float4*)(env + (size_t)pix * 16);
  dst[0] = make_float4(o[0],  o[1],  o[2],  o[3]);
  dst[1] = make_float4(o[4],  o[5],  o[6],  o[7]);
  dst[2] = make_float4(o[8],  o[9],  o[10], o[11]);
  dst[3] = make_float4(o[12], o[13], o[14], o[15]);
}

// Each thread: one output pixel, 8 of the 64 (pass,n) pairs.
// g = t>>14 in [0,8): pass = g>>2, n in [(g&3)*8, (g&3)*8+8).
__global__ __launch_bounds__(256) void k_render(
    const float* __restrict__ bs0, const float* __restrict__ bd0,
    const int* __restrict__ ix0, const int* __restrict__ iy0,
    const float* __restrict__ w0,
    const float* __restrict__ bs1, const float* __restrict__ bd1,
    const int* __restrict__ ix1, const int* __restrict__ iy1,
    const float* __restrict__ w1,
    const float* __restrict__ env, float* __restrict__ part) {
  int t = blockIdx.x * 256 + threadIdx.x;
  int g = t >> 14;
  int opix = t & (OPIX - 1);
  const float* bs; const float* bd; const int* ix; const int* iy; const float* w;
  if (g < 4) { bs = bs0; bd = bd0; ix = ix0; iy = iy0; w = w0; }
  else       { bs = bs1; bd = bd1; ix = ix1; iy = iy1; w = w1; }
  int n0 = (g & 3) * 8;

  float acc[16];
  #pragma unroll
  for (int j = 0; j < 16; j++) acc[j] = 0.f;

  #pragma unroll
  for (int k = 0; k < 8; k++) {
    int n = n0 + k;
    int off = n * OPIX + opix;
    float coef = (bd[off] + 10.0f * bs[off]) * w[n];
    int gp = iy[off] * 512 + ix[off];
    const float4* e = (const float4*)(env + (size_t)gp * 16);
    float4 e0 = e[0], e1 = e[1], e2 = e[2], e3 = e[3];
    acc[0]  = fmaf(coef, e0.x, acc[0]);
    acc[1]  = fmaf(coef, e0.y, acc[1]);
    acc[2]  = fmaf(coef, e0.z, acc[2]);
    acc[3]  = fmaf(coef, e0.w, acc[3]);
    acc[4]  = fmaf(coef, e1.x, acc[4]);
    acc[5]  = fmaf(coef, e1.y, acc[5]);
    acc[6]  = fmaf(coef, e1.z, acc[6]);
    acc[7]  = fmaf(coef, e1.w, acc[7]);
    acc[8]  = fmaf(coef, e2.x, acc[8]);
    acc[9]  = fmaf(coef, e2.y, acc[9]);
    acc[10] = fmaf(coef, e2.z, acc[10]);
    acc[11] = fmaf(coef, e2.w, acc[11]);
    acc[12] = fmaf(coef, e3.x, acc[12]);
    acc[13] = fmaf(coef, e3.y, acc[13]);
    acc[14] = fmaf(coef, e3.z, acc[14]);
    acc[15] = fmaf(coef, e3.w, acc[15]);
  }
  float4* dst = (float4*)(part + ((size_t)g * OPIX + opix) * 16);
  dst[0] = make_float4(acc[0],  acc[1],  acc[2],  acc[3]);
  dst[1] = make_float4(acc[4],  acc[5],  acc[6],  acc[7]);
  dst[2] = make_float4(acc[8],  acc[9],  acc[10], acc[11]);
  dst[3] = make_float4(acc[12], acc[13], acc[14], acc[15]);
}

// Sum the NG partials per output pixel, emit pred[0]/gt[0], per-block loss partial.
__global__ __launch_bounds__(256) void k_finalize(
    const float* __restrict__ part, float* __restrict__ d_out,
    float* __restrict__ loss_part) {
  int opix = blockIdx.x * 256 + threadIdx.x;
  float acc[16];
  #pragma unroll
  for (int j = 0; j < 16; j++) acc[j] = 0.f;
  #pragma unroll
  for (int gg = 0; gg < NG; gg++) {
    const float4* p = (const float4*)(part + ((size_t)gg * OPIX + opix) * 16);
    float4 p0 = p[0], p1 = p[1], p2 = p[2], p3 = p[3];
    acc[0] += p0.x;  acc[1] += p0.y;  acc[2]  += p0.z;  acc[3]  += p0.w;
    acc[4] += p1.x;  acc[5] += p1.y;  acc[6]  += p1.z;  acc[7]  += p1.w;
    acc[8] += p2.x;  acc[9] += p2.y;  acc[10] += p2.z;  acc[11] += p2.w;
    acc[12] += p3.x; acc[13] += p3.y; acc[14] += p3.z;  acc[15] += p3.w;
  }
  float loss = 0.f;
  #pragma unroll
  for (int c = 0; c < 3; c++) {
    float d0 = acc[c] - acc[3 + c];
    loss += d0 * d0
          + acc[6 + c]  * acc[6 + c]
          + acc[9 + c]  * acc[9 + c]
          + acc[12 + c] * acc[12 + c];
    d_out[1 + c * OPIX + opix] = acc[c];              // pred[0]
    d_out[1 + 3 * OPIX + c * OPIX + opix] = acc[3 + c]; // gt[0]
  }
  // deterministic block reduction (4 waves)
  #pragma unroll
  for (int s = 32; s > 0; s >>= 1) loss += __shfl_down(loss, s, 64);
  __shared__ float red[4];
  int lane = threadIdx.x & 63;
  int wid = threadIdx.x >> 6;
  if (lane == 0) red[wid] = loss;
  __syncthreads();
  if (threadIdx.x == 0)
    loss_part[blockIdx.x] = red[0] + red[1] + red[2] + red[3];
}

// Deterministic final reduction of the 64 block partials (no atomics).
__global__ void k_loss(const float* __restrict__ loss_part, float* __restrict__ d_out) {
  float v = loss_part[threadIdx.x];
  #pragma unroll
  for (int s = 32; s > 0; s >>= 1) v += __shfl_down(v, s, 64);
  if (threadIdx.x == 0) d_out[0] = v * (1.0f / 98304.0f); // /(PIXELS*B*3)
}

extern "C" void kernel_launch(void* const* d_in, const int* in_sizes, int n_in,
                              void* d_out, int out_size, void* d_ws, size_t ws_size,
                              hipStream_t stream) {
  const float* x   = (const float*)d_in[0];
  const float* y   = (const float*)d_in[1];
  const float* bs0 = (const float*)d_in[2];
  const float* bd0 = (const float*)d_in[3];
  const int*   ix0 = (const int*)  d_in[4];
  const int*   iy0 = (const int*)  d_in[5];
  const float* w0  = (const float*)d_in[6];
  const float* bs1 = (const float*)d_in[7];
  const float* bd1 = (const float*)d_in[8];
  const int*   ix1 = (const int*)  d_in[9];
  const int*   iy1 = (const int*)  d_in[10];
  const float* w1  = (const float*)d_in[11];
  float* out = (float*)d_out;

  float* env       = (float*)d_ws;                       // 131072*16 f32 = 8 MB
  float* part      = env + (size_t)HWE * 16;             // 8*16384*16 f32 = 8 MB
  float* loss_part = part + (size_t)NG * OPIX * 16;      // 64 f32

  hipLaunchKernelGGL(k_repack, dim3(HWE / 256), dim3(256), 0, stream, x, y, env);
  hipLaunchKernelGGL(k_render, dim3(NG * OPIX / 256), dim3(256), 0, stream,
                     bs0, bd0, ix0, iy0, w0, bs1, bd1, ix1, iy1, w1, env, part);
  hipLaunchKernelGGL(k_finalize, dim3(OPIX / 256), dim3(256), 0, stream,
                     part, out, loss_part);
  hipLaunchKernelGGL(k_loss, dim3(1), dim3(64), 0, stream, loss_part, out);
}